// Round 5
// baseline (306.121 us; speedup 1.0000x reference)
//
#include <hip/hip_runtime.h>
#include <cmath>

#define SEQ 2048
#define BATCH 2
#define HID 1024
#define NH 16
#define NKV 4
#define DH 64
#define KVDIM 256
#define K32C 32          // K=1024 -> 32 chunks of 32

typedef __attribute__((ext_vector_type(8))) short bf16x8;
typedef __attribute__((ext_vector_type(4))) float f32x4;

static __device__ __forceinline__ unsigned short f2bf(float x) {
  union { float f; unsigned u; } v; v.f = x;
  unsigned r = v.u + 0x7fffu + ((v.u >> 16) & 1u);  // RNE
  return (unsigned short)(r >> 16);
}
static __device__ __forceinline__ float bf2f(unsigned short h) {
  union { unsigned u; float f; } v; v.u = ((unsigned)h) << 16;
  return v.f;
}
static __device__ __forceinline__ void gl_lds16(const unsigned short* g, unsigned short* l) {
  __builtin_amdgcn_global_load_lds(
      (const __attribute__((address_space(1))) unsigned int*)g,
      (__attribute__((address_space(3))) unsigned int*)l, 16, 0, 0);
}

// ---- pack A (fp32 [M][K=1024] row-major -> MFMA-A-frag-major bf16 hi[,lo]) ----
template<bool HILO>
__global__ __launch_bounds__(256) void pack_a_kernel(
    const float* __restrict__ A, unsigned short* __restrict__ hi,
    unsigned short* __restrict__ lo) {
  int gid = blockIdx.x * 256 + threadIdx.x;
  int lane = gid & 63;
  int k32 = (gid >> 6) & 31;
  int m16 = gid >> 11;
  int quad = lane >> 4, l16 = lane & 15;
  const float* src = A + (size_t)(m16 * 16 + l16) * 1024 + k32 * 32 + quad * 8;
  float4 a0 = *(const float4*)src;
  float4 a1 = *(const float4*)(src + 4);
  float v[8] = {a0.x, a0.y, a0.z, a0.w, a1.x, a1.y, a1.z, a1.w};
  unsigned short h[8], l[8];
#pragma unroll
  for (int j = 0; j < 8; ++j) {
    h[j] = f2bf(v[j]);
    if (HILO) l[j] = f2bf(v[j] - bf2f(h[j]));
  }
  *(bf16x8*)(hi + (size_t)gid * 8) = *(bf16x8*)h;
  if (HILO) *(bf16x8*)(lo + (size_t)gid * 8) = *(bf16x8*)l;
}

// ---- pack A variant: normalize attention partials by l, then hi/lo split ----
__global__ __launch_bounds__(256) void pack_a_norm_kernel(
    const float* __restrict__ A, const float* __restrict__ lpart,
    unsigned short* __restrict__ hi, unsigned short* __restrict__ lo) {
  int gid = blockIdx.x * 256 + threadIdx.x;
  int lane = gid & 63;
  int k32 = (gid >> 6) & 31;
  int m16 = gid >> 11;
  int quad = lane >> 4, l16 = lane & 15;
  int m = m16 * 16 + l16;
  int b = m >> 11, s = m & 2047;
  int k0 = k32 * 32 + quad * 8;
  int h = k0 >> 6;
  float inv = 1.0f / lpart[(size_t)(b * NH + h) * SEQ + s];
  const float* src = A + (size_t)m * 1024 + k0;
  float4 a0 = *(const float4*)src;
  float4 a1 = *(const float4*)(src + 4);
  float v[8] = {a0.x, a0.y, a0.z, a0.w, a1.x, a1.y, a1.z, a1.w};
  unsigned short hh[8], ll[8];
#pragma unroll
  for (int j = 0; j < 8; ++j) {
    float x = v[j] * inv;
    hh[j] = f2bf(x);
    ll[j] = f2bf(x - bf2f(hh[j]));
  }
  *(bf16x8*)(hi + (size_t)gid * 8) = *(bf16x8*)hh;
  *(bf16x8*)(lo + (size_t)gid * 8) = *(bf16x8*)ll;
}

// ---- pack B (fp32 W [K=1024][Nsrc] -> MFMA-B-frag-major bf16 hi[,lo]) ----
template<bool HILO>
__global__ __launch_bounds__(256) void pack_b_kernel(
    const float* __restrict__ W, unsigned short* __restrict__ hi,
    unsigned short* __restrict__ lo, int Nsrc) {
  int gid = blockIdx.x * 256 + threadIdx.x;
  int lane = gid & 63;
  int k32 = (gid >> 6) & 31;
  int n16 = gid >> 11;
  int quad = lane >> 4, l16 = lane & 15;
  int n = n16 * 16 + l16, k = k32 * 32 + quad * 8;
  unsigned short h[8], l[8];
#pragma unroll
  for (int j = 0; j < 8; ++j) {
    float v = W[(size_t)(k + j) * Nsrc + n];
    h[j] = f2bf(v);
    if (HILO) l[j] = f2bf(v - bf2f(h[j]));
  }
  *(bf16x8*)(hi + (size_t)gid * 8) = *(bf16x8*)h;
  if (HILO) *(bf16x8*)(lo + (size_t)gid * 8) = *(bf16x8*)l;
}

__global__ __launch_bounds__(256) void bias_cat_kernel(
    const float* __restrict__ bq, const float* __restrict__ bk,
    const float* __restrict__ bv, float* __restrict__ dst) {
  int n = blockIdx.x * 256 + threadIdx.x;
  if (n < 1536)
    dst[n] = (n < 1024) ? bq[n] : (n < 1280 ? bk[n - 1024] : bv[n - 1280]);
}

// ---- packed-input MFMA GEMM (unchanged) ----
template<int CHAINS, bool OUTBF16>
__global__ __launch_bounds__(256) void gemm_pk_kernel(
    const unsigned short* __restrict__ Ah, const unsigned short* __restrict__ Al,
    const unsigned short* __restrict__ Bh, const unsigned short* __restrict__ Bl,
    const float* __restrict__ bias, void* __restrict__ Cout, int N) {
  constexpr int NCH = (CHAINS == 3) ? 2 : 1;
  __shared__ unsigned short Asm[NCH][4 * 512];
  __shared__ unsigned short Bsm[NCH][8 * 512];
  const int tid = threadIdx.x;
  const int wave = tid >> 6, lane = tid & 63;
  const int wr = wave >> 1, wc = wave & 1;
  const int quad = lane >> 4, l16 = lane & 15;
  const size_t abase = ((size_t)(blockIdx.y * 4 + wave) * K32C) * 64 + lane;
  const size_t bbase0 = ((size_t)(blockIdx.x * 8 + wave) * K32C) * 64 + lane;
  const size_t bbase1 = ((size_t)(blockIdx.x * 8 + wave + 4) * K32C) * 64 + lane;
  f32x4 acc[2][4] = {};
  for (int k32 = 0; k32 < K32C; ++k32) {
    __syncthreads();
    gl_lds16(Ah + (abase + (size_t)k32 * 64) * 8, &Asm[0][wave * 512]);
    gl_lds16(Bh + (bbase0 + (size_t)k32 * 64) * 8, &Bsm[0][wave * 512]);
    gl_lds16(Bh + (bbase1 + (size_t)k32 * 64) * 8, &Bsm[0][(wave + 4) * 512]);
    if (CHAINS == 3) {
      gl_lds16(Al + (abase + (size_t)k32 * 64) * 8, &Asm[1][wave * 512]);
      gl_lds16(Bl + (bbase0 + (size_t)k32 * 64) * 8, &Bsm[1][wave * 512]);
      gl_lds16(Bl + (bbase1 + (size_t)k32 * 64) * 8, &Bsm[1][(wave + 4) * 512]);
    }
    __syncthreads();
    bf16x8 af[2][NCH], bfr[4][NCH];
#pragma unroll
    for (int mt = 0; mt < 2; ++mt)
#pragma unroll
      for (int ch = 0; ch < NCH; ++ch)
        af[mt][ch] = *(const bf16x8*)&Asm[ch][((wr * 2 + mt) * 64 + lane) * 8];
#pragma unroll
    for (int nt = 0; nt < 4; ++nt)
#pragma unroll
      for (int ch = 0; ch < NCH; ++ch)
        bfr[nt][ch] = *(const bf16x8*)&Bsm[ch][((wc * 4 + nt) * 64 + lane) * 8];
#pragma unroll
    for (int mt = 0; mt < 2; ++mt)
#pragma unroll
      for (int nt = 0; nt < 4; ++nt) {
        acc[mt][nt] = __builtin_amdgcn_mfma_f32_16x16x32_bf16(af[mt][0], bfr[nt][0], acc[mt][nt], 0, 0, 0);
        if (CHAINS == 3) {
          acc[mt][nt] = __builtin_amdgcn_mfma_f32_16x16x32_bf16(af[mt][1], bfr[nt][0], acc[mt][nt], 0, 0, 0);
          acc[mt][nt] = __builtin_amdgcn_mfma_f32_16x16x32_bf16(af[mt][0], bfr[nt][1], acc[mt][nt], 0, 0, 0);
        }
      }
  }
  const int n0 = blockIdx.x * 128 + wc * 64;
  const int m0 = blockIdx.y * 64 + wr * 32;
#pragma unroll
  for (int mt = 0; mt < 2; ++mt)
#pragma unroll
    for (int nt = 0; nt < 4; ++nt)
#pragma unroll
      for (int r = 0; r < 4; ++r) {
        int gm = m0 + mt * 16 + quad * 4 + r;
        int n = n0 + nt * 16 + l16;
        float v = acc[mt][nt][r] + bias[n];
        if (OUTBF16)
          ((unsigned short*)Cout)[(size_t)gm * N + n] = f2bf(v);
        else
          ((float*)Cout)[(size_t)gm * N + n] = v;
      }
}

// ---- RoPE(half=512) + rmsnorm, Q -> A-frag-major packed bf16 hi/lo ---------
__global__ __launch_bounds__(1024) void rope_norm_q_kernel(
    const unsigned short* __restrict__ qkv, unsigned short* __restrict__ Qh,
    unsigned short* __restrict__ Ql) {
  const int s = blockIdx.x, b = blockIdx.y;
  const int t = threadIdx.x;
  const unsigned short* row = qkv + ((size_t)b * SEQ + s) * 1536;
  const int j = t & 511;
  float invf = exp2f((float)j * (-13.287712379549449f / 512.0f));
  float ang = (float)s * invf;
  float c = cosf(ang), sn = sinf(ang);
  float x1 = bf2f(row[j]), x2 = bf2f(row[j + 512]);
  float val = (t < 512) ? (x1 * c - x2 * sn) : (x2 * c + x1 * sn);
  float ss = val * val;
#pragma unroll
  for (int off = 1; off < 64; off <<= 1) ss += __shfl_xor(ss, off);
  float rn = rsqrtf(ss * (1.0f / 64.0f) + 1.1920929e-07f);
  float v = val * rn;
  unsigned short hi = f2bf(v);
  unsigned short lo = f2bf(v - bf2f(hi));
  int h = t >> 6, d = t & 63;
  size_t o = (size_t)(b * NH + h) * 131072 +
             ((((size_t)(s >> 4) * 2 + (d >> 5)) * 64) + ((d >> 3) & 3) * 16 + (s & 15)) * 8 + (d & 7);
  Qh[o] = hi;
  Ql[o] = lo;
}

// ---- RoPE(half=128)+rmsnorm K -> B-frag-major hi; V -> B-frag-major --------
__global__ __launch_bounds__(256) void rope_norm_kv_kernel(
    const unsigned short* __restrict__ qkv, unsigned short* __restrict__ Kpk,
    unsigned short* __restrict__ Vpk) {
  const int s = blockIdx.x, b = blockIdx.y;
  const int t = threadIdx.x;
  const unsigned short* row = qkv + ((size_t)b * SEQ + s) * 1536;
  const int j = t & 127;
  float invf = exp2f((float)j * (-13.287712379549449f / 128.0f));
  float ang = (float)s * invf;
  float c = cosf(ang), sn = sinf(ang);
  float x1 = bf2f(row[1024 + j]), x2 = bf2f(row[1024 + 128 + j]);
  float val = (t < 128) ? (x1 * c - x2 * sn) : (x2 * c + x1 * sn);
  float ss = val * val;
#pragma unroll
  for (int off = 1; off < 64; off <<= 1) ss += __shfl_xor(ss, off);
  float rn = rsqrtf(ss * (1.0f / 64.0f) + 1.1920929e-07f);
  float kv = val * rn;
  int h = t >> 6, d = t & 63;
  size_t ko = (size_t)(b * NKV + h) * 131072 +
              ((((size_t)(s >> 4) * 2 + (d >> 5)) * 64) + ((d >> 3) & 3) * 16 + (s & 15)) * 8 + (d & 7);
  Kpk[ko] = f2bf(kv);
  size_t vo = (size_t)(b * NKV + h) * 131072 +
              ((((size_t)(d >> 4) * 64 + (s >> 5)) * 64) + ((s >> 3) & 3) * 16 + (d & 15)) * 8 + (s & 7);
  Vpk[vo] = row[1280 + t];
}

// ------------------------- MFMA attention v3: barrier-free ------------------
// grid (SEQ/32, NKV*2, BATCH) = 1024 blocks; 4 waves = 4 q-heads of one kv
// group; j-range split 2-way. NO __syncthreads anywhere: K/V B-frags loaded
// directly global->VGPR from the frag-major packed arrays (all 4 waves read
// identical addresses -> L1 dedup); mask read as direct dword loads; only
// LDS use is the per-wave P C->A re-layout (single-wave ordering, no barrier).
// Softmax: fixed max=8 (rmsnorm bound), p=exp2(C*0.125*log2e + (m-8)*log2e).
// l via MFMA against ones-B. Partials accumulated with fp32 atomicAdd.
__global__ __launch_bounds__(256, 3) void attn_mfma3_kernel(
    const unsigned short* __restrict__ Qh, const unsigned short* __restrict__ Ql,
    const unsigned short* __restrict__ Kpk, const unsigned short* __restrict__ Vpk,
    const float* __restrict__ mask, float* __restrict__ attn_po,
    float* __restrict__ l_part) {
  __shared__ unsigned short Ps[4][32 * 72];

  const int b = blockIdx.z;
  const int kvh = blockIdx.y >> 1, jh = blockIdx.y & 1;
  const int q0 = blockIdx.x * 32;
  const int tid = threadIdx.x, wave = tid >> 6, lane = tid & 63;
  const int quad = lane >> 4, l16 = lane & 15;
  const int h = kvh * 4 + wave;

  bf16x8 qh[2][2], ql[2][2];
  {
    const unsigned short* Qb_h = Qh + (size_t)(b * NH + h) * 131072;
    const unsigned short* Qb_l = Ql + (size_t)(b * NH + h) * 131072;
#pragma unroll
    for (int mt = 0; mt < 2; ++mt)
#pragma unroll
      for (int kf = 0; kf < 2; ++kf) {
        size_t o = ((((size_t)(q0 >> 4) + mt) * 2 + kf) * 64 + lane) * 8;
        qh[mt][kf] = *(const bf16x8*)(Qb_h + o);
        ql[mt][kf] = *(const bf16x8*)(Qb_l + o);
      }
  }

  const unsigned short* Kbase = Kpk + (size_t)(b * NKV + kvh) * 131072;
  const unsigned short* Vbase = Vpk + (size_t)(b * NKV + kvh) * 131072;
  const float* mbase = mask + ((size_t)b * SEQ + q0) * SEQ;  // [32][SEQ] tile rows

  bf16x8 ones;
#pragma unroll
  for (int i = 0; i < 8; ++i) ones[i] = (short)0x3F80;  // bf16 1.0

  f32x4 O[2][4] = {};
  f32x4 lAcc[2] = {};

  const int jbase = jh * (SEQ / 2);
  constexpr float SC = 0.18033688011112042f;   // 0.125 * log2(e)
  constexpr float L2E = 1.4426950408889634f;   // log2(e)
  constexpr float MOFF = -11.541560327111707f; // -8 * log2(e)

  for (int jc = 0; jc < 32; ++jc) {
    const int j0 = jbase + jc * 32;

    // K/V B-fragments: direct global->VGPR (coalesced 1 KiB per load)
    bf16x8 kbf[2][2], vbf[4];
#pragma unroll
    for (int nt = 0; nt < 2; ++nt)
#pragma unroll
      for (int kf = 0; kf < 2; ++kf)
        kbf[nt][kf] = *(const bf16x8*)(Kbase +
            ((((size_t)(j0 >> 4) + nt) * 2 + kf) * 64 + lane) * 8);
#pragma unroll
    for (int d16 = 0; d16 < 4; ++d16)
      vbf[d16] = *(const bf16x8*)(Vbase +
          (((size_t)d16 * 64 + (j0 >> 5)) * 64 + lane) * 8);

#pragma unroll
    for (int mt = 0; mt < 2; ++mt)
#pragma unroll
      for (int nt = 0; nt < 2; ++nt) {
        f32x4 C = {};
        C = __builtin_amdgcn_mfma_f32_16x16x32_bf16(qh[mt][0], kbf[nt][0], C, 0, 0, 0);
        C = __builtin_amdgcn_mfma_f32_16x16x32_bf16(qh[mt][1], kbf[nt][1], C, 0, 0, 0);
        C = __builtin_amdgcn_mfma_f32_16x16x32_bf16(ql[mt][0], kbf[nt][0], C, 0, 0, 0);
        C = __builtin_amdgcn_mfma_f32_16x16x32_bf16(ql[mt][1], kbf[nt][1], C, 0, 0, 0);
#pragma unroll
        for (int r = 0; r < 4; ++r) {
          int row = mt * 16 + quad * 4 + r;
          float m = mbase[(size_t)row * SEQ + j0 + nt * 16 + l16];
          float p = exp2f(fmaf(C[r], SC, fmaf(m, L2E, MOFF)));
          union { float f; unsigned u; } pu; pu.f = p;
          Ps[wave][row * 72 + nt * 16 + l16] = (unsigned short)((pu.u + 0x8000u) >> 16);
        }
      }

    bf16x8 pa[2];
#pragma unroll
    for (int mt = 0; mt < 2; ++mt)
      pa[mt] = *(const bf16x8*)&Ps[wave][(mt * 16 + l16) * 72 + quad * 8];
#pragma unroll
    for (int mt = 0; mt < 2; ++mt) {
      lAcc[mt] = __builtin_amdgcn_mfma_f32_16x16x32_bf16(pa[mt], ones, lAcc[mt], 0, 0, 0);
#pragma unroll
      for (int nt = 0; nt < 4; ++nt)
        O[mt][nt] = __builtin_amdgcn_mfma_f32_16x16x32_bf16(pa[mt], vbf[nt], O[mt][nt], 0, 0, 0);
    }
  }

#pragma unroll
  for (int mt = 0; mt < 2; ++mt)
#pragma unroll
    for (int r = 0; r < 4; ++r) {
      int s = q0 + mt * 16 + quad * 4 + r;
#pragma unroll
      for (int nt = 0; nt < 4; ++nt)
        atomicAdd(attn_po + ((size_t)b * SEQ + s) * HID + h * DH + nt * 16 + l16,
                  O[mt][nt][r]);
      if (l16 == 0)
        atomicAdd(l_part + (size_t)(b * NH + h) * SEQ + s, lAcc[mt][r]);
    }
}

extern "C" void kernel_launch(void* const* d_in, const int* in_sizes, int n_in,
                              void* d_out, int out_size, void* d_ws, size_t ws_size,
                              hipStream_t stream) {
  const float* hs   = (const float*)d_in[0];
  const float* mask = (const float*)d_in[1];
  const float* Wq   = (const float*)d_in[2];
  const float* bq   = (const float*)d_in[3];
  const float* Wk   = (const float*)d_in[4];
  const float* bk   = (const float*)d_in[5];
  const float* Wv   = (const float*)d_in[6];
  const float* bv   = (const float*)d_in[7];
  const float* Wo   = (const float*)d_in[8];
  const float* bo   = (const float*)d_in[9];
  float* out = (float*)d_out;
  char* ws = (char*)d_ws;
  const size_t MiB = 1048576;

  unsigned short* hs_pk   = (unsigned short*)(ws);              // [0,8) dead after QKV gemm
  unsigned short* qkvproj = (unsigned short*)(ws + 8 * MiB);    // [8,20) dead after rope
  float*          attn_po = (float*)(ws);                       // [0,16) after rope
  float*          l_part  = (float*)(ws + 16 * MiB);            // [16,16.25)
  unsigned short* Wqkv_hi = (unsigned short*)(ws + 20 * MiB);   // [20,23) dead after QKV gemm
  unsigned short* Wo_hi   = (unsigned short*)(ws + 20 * MiB);   // [20,22) after QKV gemm
  unsigned short* Wo_lo   = (unsigned short*)(ws + 22 * MiB);   // [22,24)
  unsigned short* Qpk_h   = (unsigned short*)(ws + 24 * MiB);   // [24,32) dead after attn
  unsigned short* Qpk_l   = (unsigned short*)(ws + 32 * MiB);   // [32,40) dead after attn
  unsigned short* ao_hi   = (unsigned short*)(ws + 24 * MiB);   // reuse
  unsigned short* ao_lo   = (unsigned short*)(ws + 32 * MiB);   // reuse
  unsigned short* Kpk     = (unsigned short*)(ws + 40 * MiB);   // [40,42)
  unsigned short* Vpk     = (unsigned short*)(ws + 42 * MiB);   // [42,44)
  float*          bias_c  = (float*)(ws + 44 * MiB);            // 6 KB

  // --- pack inputs ---
  pack_a_kernel<false><<<2048, 256, 0, stream>>>(hs, hs_pk, nullptr);
  pack_b_kernel<false><<<512, 256, 0, stream>>>(Wq, Wqkv_hi, nullptr, 1024);
  pack_b_kernel<false><<<128, 256, 0, stream>>>(Wk, Wqkv_hi + (size_t)64 * 2048 * 8, nullptr, 256);
  pack_b_kernel<false><<<128, 256, 0, stream>>>(Wv, Wqkv_hi + (size_t)80 * 2048 * 8, nullptr, 256);
  bias_cat_kernel<<<6, 256, 0, stream>>>(bq, bk, bv, bias_c);

  // --- fused QKV projection (bf16 MFMA, N=1536) ---
  gemm_pk_kernel<1, true><<<dim3(12, 64), 256, 0, stream>>>(
      hs_pk, nullptr, Wqkv_hi, nullptr, bias_c, qkvproj, 1536);

  pack_b_kernel<true><<<512, 256, 0, stream>>>(Wo, Wo_hi, Wo_lo, 1024);

  // --- rope + rmsnorm -> frag-major packed Q/K/V ---
  rope_norm_q_kernel<<<dim3(SEQ, BATCH), dim3(1024), 0, stream>>>(qkvproj, Qpk_h, Qpk_l);
  rope_norm_kv_kernel<<<dim3(SEQ, BATCH), dim3(256), 0, stream>>>(qkvproj, Kpk, Vpk);

  // --- zero partial accumulators, then barrier-free attention ---
  hipMemsetAsync(ws, 0, 16 * MiB + 262144, stream);
  attn_mfma3_kernel<<<dim3(SEQ / 32, NKV * 2, BATCH), 256, 0, stream>>>(
      Qpk_h, Qpk_l, Kpk, Vpk, mask, attn_po, l_part);

  // --- O projection: normalize+pack, then 3-chain MFMA GEMM ---
  pack_a_norm_kernel<<<2048, 256, 0, stream>>>(attn_po, l_part, ao_hi, ao_lo);
  gemm_pk_kernel<3, false><<<dim3(8, 64), 256, 0, stream>>>(
      ao_hi, ao_lo, Wo_hi, Wo_lo, bo, out, 1024);
}